// Round 1
// baseline (505.643 us; speedup 1.0000x reference)
//
#include <hip/hip_runtime.h>
#include <cstdint>
#include <cstddef>

// ---------------------------------------------------------------------------
// NN_each_LN_exp: all 33x33 SAME convs on 32x32 maps are dense 1024x1024
// linear operators -> everything becomes f16 MFMA GEMMs with fused epilogues.
// Row layout for per-color maps: r = n*4 + k  (so MFMA acc quad holds all 4 k
// of one (n,o) cell -> sigmoid/mask fusion is lane-local).
// ---------------------------------------------------------------------------

typedef _Float16 f16;
typedef __attribute__((ext_vector_type(8))) _Float16 f16x8;
typedef __attribute__((ext_vector_type(4))) float f32x4;

#define NB   4096          // batch
#define PIX  1024          // 32*32
#define MR   (NB * 4)      // color-expanded rows

__device__ __forceinline__ void gld_lds16(const void* g, void* l) {
    // async global->LDS, 16B/lane; LDS dst is wave-uniform base + lane*16
    __builtin_amdgcn_global_load_lds(
        (const __attribute__((address_space(1))) void*)g,
        (__attribute__((address_space(3))) void*)l, 16, 0, 0);
}

// Build the 4 conv matrices (1024x1024 f16): M[o][in] = w[a-i+16][b-j+16]
__global__ void build_mats(const float* __restrict__ we, const float* __restrict__ wn,
                           const float* __restrict__ wn2, const float* __restrict__ wem,
                           f16* __restrict__ Me, f16* __restrict__ Mn,
                           f16* __restrict__ Mn2, f16* __restrict__ Mem) {
    int idx = blockIdx.x * 256 + threadIdx.x;      // over 1024*1024
    int o = idx >> 10, in = idx & 1023;
    int i = o >> 5, j = o & 31, a = in >> 5, b = in & 31;
    int u = a - i + 16, v = b - j + 16;
    bool ok = (u >= 0) && (u < 33) && (v >= 0) && (v < 33);
    int w = u * 33 + v;
    float ve = 0.f, vn = 0.f, vn2 = 0.f, vem = 0.f;
    if (ok) { ve = we[w]; vn = wn[w]; vn2 = wn2[w]; vem = wem[w]; }
    Me[idx]  = (f16)ve;
    Mn[idx]  = (f16)vn;
    Mn2[idx] = (f16)vn2;
    Mem[idx] = (f16)vem;
}

// W1 (100,1024) fp32 -> padded (128,1024) f16
__global__ void build_w1(const float* __restrict__ W1, f16* __restrict__ W1b) {
    int idx = blockIdx.x * 256 + threadIdx.x;      // over 128*1024
    int j = idx >> 10, i = idx & 1023;
    W1b[idx] = (f16)(j < 100 ? W1[j * 1024 + i] : 0.f);
}

// dots (34,32,4096) int32 -> one-hot f16 operand arrays + board bytes
__global__ void build_masks(const int* __restrict__ dots, f16* __restrict__ Xe,
                            f16* __restrict__ Xn, f16* __restrict__ Xz,
                            unsigned char* __restrict__ board) {
    int idx = blockIdx.x * 256 + threadIdx.x;      // idx = n*1024 + p
    int n = idx >> 10, p = idx & 1023;
    int c = dots[p * 4096 + n];                    // (v,h,b) flat with p=v*32+h
    board[idx] = (unsigned char)c;
    Xz[idx] = (f16)(c == 0 ? 1.f : 0.f);
    int base = n * 4096 + p;                       // row (n*4+k), col p
#pragma unroll
    for (int k = 0; k < 4; k++) {
        Xe[base + k * 1024] = (f16)((c == k + 1) ? 1.f : 0.f);
        Xn[base + k * 1024] = (f16)((c != 0 && c != k + 1) ? 1.f : 0.f);
    }
}

// ---------------------------------------------------------------------------
// GEMM: C(M x N) = X(M x K) * Mt(N x K)^T, f16 in, fp32 acc.
// BM=BN=128, BK=64, 256 thr = 4 waves (2x2 of 64x64), 16x16x32 MFMA.
// XOR-swizzled LDS chunks to break ds_read_b128 bank conflicts.
// MODE: 0 f16-out  1 f32-out  2 stage1-fused  3 depth-fused
//       4 depth-final(writes feat)  5 f32-out+leakyrelu
// ---------------------------------------------------------------------------
template <int MODE>
__global__ void __launch_bounds__(256, 2) gemm_k(
    const f16* __restrict__ X, const f16* __restrict__ Mt, int K,
    float* __restrict__ outF, f16* __restrict__ outB, int ldo,
    const float* __restrict__ En, const unsigned char* __restrict__ board,
    const f16* __restrict__ NC, float* __restrict__ Lsel,
    f16* __restrict__ Pout, f16* __restrict__ feat) {
    __shared__ __attribute__((aligned(16))) char smem[32768];
    char* smA = smem;
    char* smB = smem + 16384;
    const int tid = threadIdx.x;
    const int wv = tid >> 6, ln = tid & 63;
    const int wm = wv >> 1, wn_ = wv & 1;
    const int lr = ln & 15, lq = ln >> 4;
    const int rtile = blockIdx.y * 128, otile = blockIdx.x * 128;

    const f32x4 fz = {0.f, 0.f, 0.f, 0.f};
    f32x4 acc[4][4];
#pragma unroll
    for (int i = 0; i < 4; i++)
#pragma unroll
        for (int j = 0; j < 4; j++) acc[i][j] = fz;

    for (int kb = 0; kb < K; kb += 64) {
#pragma unroll
        for (int t = 0; t < 4; t++) {
            int c = (wv * 4 + t) * 64 + ln;        // chunk id 0..1023
            int row = c >> 3;
            int gcol = (c & 7) ^ (row & 7);        // logical col chunk for this slot
            gld_lds16(X  + (size_t)(rtile + row) * K + kb + gcol * 8,
                      smA + (wv * 4 + t) * 1024);
            gld_lds16(Mt + (size_t)(otile + row) * K + kb + gcol * 8,
                      smB + (wv * 4 + t) * 1024);
        }
        __syncthreads();
#pragma unroll
        for (int kk = 0; kk < 2; kk++) {
            f16x8 af[4], bfr[4];
#pragma unroll
            for (int i = 0; i < 4; i++) {
                int rrow = wm * 64 + i * 16 + lr;
                int phys = (kk * 4 + lq) ^ (rrow & 7);
                af[i] = *(const f16x8*)(smA + rrow * 128 + phys * 16);
            }
#pragma unroll
            for (int j = 0; j < 4; j++) {
                int brow = wn_ * 64 + j * 16 + lr;
                int phys = (kk * 4 + lq) ^ (brow & 7);
                bfr[j] = *(const f16x8*)(smB + brow * 128 + phys * 16);
            }
#pragma unroll
            for (int i = 0; i < 4; i++)
#pragma unroll
                for (int j = 0; j < 4; j++)
                    acc[i][j] = __builtin_amdgcn_mfma_f32_16x16x32_f16(
                        af[i], bfr[j], acc[i][j], 0, 0, 0);
        }
        __syncthreads();
    }

    // epilogue: lane (i,j) holds C[rbase+v][o], v=0..3; rbase = n*4 in fused modes
#pragma unroll
    for (int i = 0; i < 4; i++) {
        int rbase = rtile + wm * 64 + i * 16 + lq * 4;
#pragma unroll
        for (int j = 0; j < 4; j++) {
            int o = otile + wn_ * 64 + j * 16 + lr;
            f32x4 a = acc[i][j];
            if (MODE == 0) {
#pragma unroll
                for (int v = 0; v < 4; v++)
                    outB[(size_t)(rbase + v) * ldo + o] = (f16)a[v];
            } else if (MODE == 1) {
#pragma unroll
                for (int v = 0; v < 4; v++)
                    outF[(size_t)(rbase + v) * ldo + o] = a[v];
            } else if (MODE == 5) {
#pragma unroll
                for (int v = 0; v < 4; v++) {
                    float x = a[v];
                    outF[(size_t)(rbase + v) * ldo + o] = x > 0.f ? x : 0.2f * x;
                }
            } else {  // 2, 3, 4: fused board logic; exactly one color live per cell
                int n = rbase >> 2;
                size_t no = (size_t)n * PIX + o;
                int c = board[no];
                float E = En[no];
                float asel = (c == 1) ? a[0] : (c == 2) ? a[1] : (c == 3) ? a[2] : a[3];
                float nc0 = 0.f, nc1 = 0.f, nc2 = 0.f, nc3 = 0.f;
                if (MODE == 2 || MODE == 3) {
                    nc0 = (float)NC[(size_t)(rbase + 0) * PIX + o];
                    nc1 = (float)NC[(size_t)(rbase + 1) * PIX + o];
                    nc2 = (float)NC[(size_t)(rbase + 2) * PIX + o];
                    nc3 = (float)NC[(size_t)(rbase + 3) * PIX + o];
                }
                float Lnew;
                if (MODE == 2) {
                    float ncsel = (c == 1) ? nc0 : (c == 2) ? nc1 : (c == 3) ? nc2 : nc3;
                    Lnew = (c > 0) ? (asel + E - ncsel) : 0.f;   // L0 = each*(A+E-NC)
                } else {
                    float Lold = Lsel[no];
                    Lnew = (c > 0) ? (Lold + E + asel) : 0.f;    // L = each*(L+E+C)
                }
                float s = 1.f / (1.f + expf(-Lnew));             // empty cell -> 0.5
                if (MODE == 4) {
                    feat[no] = (f16)s;
                } else {
                    Lsel[no] = Lnew;
                    Pout[(size_t)(rbase + 0) * PIX + o] = (f16)(nc0 * s);
                    Pout[(size_t)(rbase + 1) * PIX + o] = (f16)(nc1 * s);
                    Pout[(size_t)(rbase + 2) * PIX + o] = (f16)(nc2 * s);
                    Pout[(size_t)(rbase + 3) * PIX + o] = (f16)(nc3 * s);
                }
            }
        }
    }
}

// MLP layers 2+3: x2 = leaky(x1 @ W2^T); out = x2 @ W3^T. 64 batches/block.
__global__ void __launch_bounds__(256) mlp23(const float* __restrict__ X1,
                                             const float* __restrict__ W2,
                                             const float* __restrict__ W3,
                                             float* __restrict__ out) {
    __shared__ float sW2[10000];
    __shared__ float sW3[100];
    __shared__ float red[256];
    int t = threadIdx.x;
    for (int idx = t; idx < 10000; idx += 256) sW2[idx] = W2[idx];
    if (t < 100) sW3[t] = W3[t];
    __syncthreads();
    int nb = t >> 2, q = t & 3;
    int n = blockIdx.x * 64 + nb;
    const float* x1 = X1 + (size_t)n * 128;
    float xr[100];
#pragma unroll
    for (int i = 0; i < 100; i++) xr[i] = x1[i];
    float partial = 0.f;
    for (int jj = 0; jj < 25; jj++) {
        int j = q + jj * 4;
        const float* w2r = sW2 + j * 100;
        float acc2 = 0.f;
#pragma unroll
        for (int i = 0; i < 100; i++) acc2 += w2r[i] * xr[i];
        partial += sW3[j] * (acc2 > 0.f ? acc2 : 0.2f * acc2);
    }
    red[t] = partial;
    __syncthreads();
    if (q == 0) out[n] = red[t] + red[t + 1] + red[t + 2] + red[t + 3];
}

extern "C" void kernel_launch(void* const* d_in, const int* in_sizes, int n_in,
                              void* d_out, int out_size, void* d_ws, size_t ws_size,
                              hipStream_t stream) {
    (void)in_sizes; (void)n_in; (void)out_size; (void)ws_size;
    const int*   dots  = (const int*)d_in[0];
    const float* w_each = (const float*)d_in[1];
    const float* w_not  = (const float*)d_in[2];
    const float* w_not2 = (const float*)d_in[3];
    const float* w_emp  = (const float*)d_in[4];
    const float* W1 = (const float*)d_in[5];
    const float* W2 = (const float*)d_in[6];
    const float* W3 = (const float*)d_in[7];
    float* out = (float*)d_out;

    char* ws = (char*)d_ws;
    size_t off = 0;
    auto alloc = [&](size_t bytes) -> char* {
        char* p = ws + off;
        off += (bytes + 255) & ~(size_t)255;
        return p;
    };
    f16* Me   = (f16*)alloc((size_t)1024 * 1024 * 2);
    f16* Mn   = (f16*)alloc((size_t)1024 * 1024 * 2);
    f16* Mn2  = (f16*)alloc((size_t)1024 * 1024 * 2);
    f16* Mem  = (f16*)alloc((size_t)1024 * 1024 * 2);
    f16* W1b  = (f16*)alloc((size_t)128 * 1024 * 2);
    f16* Xe   = (f16*)alloc((size_t)MR * PIX * 2);   // reused as Pb after stage1
    f16* Xn   = (f16*)alloc((size_t)MR * PIX * 2);   // reused as Pa after NC-GEMM
    f16* Xz   = (f16*)alloc((size_t)NB * PIX * 2);   // reused as feat after En-GEMM
    unsigned char* board = (unsigned char*)alloc((size_t)NB * PIX);
    f16*   NC   = (f16*)alloc((size_t)MR * PIX * 2);
    float* En   = (float*)alloc((size_t)NB * PIX * 4);
    float* Lsel = (float*)alloc((size_t)NB * PIX * 4);
    float* X1   = (float*)alloc((size_t)NB * 128 * 4);

    build_mats<<<4096, 256, 0, stream>>>(w_each, w_not, w_not2, w_emp, Me, Mn, Mn2, Mem);
    build_w1<<<512, 256, 0, stream>>>(W1, W1b);
    build_masks<<<16384, 256, 0, stream>>>(dots, Xe, Xn, Xz, board);

    dim3 blk(256);
    dim3 gBig(8, 128);    // 16384 x 1024
    dim3 gSmall(8, 32);   // 4096 x 1024
    dim3 gMlp(1, 32);     // 4096 x 128

    // NC[r] = conv(notm[k], w_not)
    gemm_k<0><<<gBig, blk, 0, stream>>>(Xn, Mn, 1024, nullptr, NC, 1024,
                                        nullptr, nullptr, nullptr, nullptr, nullptr, nullptr);
    // En[n] = conv(empty, w_empty)
    gemm_k<1><<<gSmall, blk, 0, stream>>>(Xz, Mem, 1024, En, nullptr, 1024,
                                          nullptr, nullptr, nullptr, nullptr, nullptr, nullptr);
    f16* Pa = Xn;   // Xn dead after NC-GEMM
    f16* Pb = Xe;   // Xe dead after stage1
    // stage1: A = conv(each, w_each); fused L0/sigmoid/P1
    gemm_k<2><<<gBig, blk, 0, stream>>>(Xe, Me, 1024, nullptr, nullptr, 1024,
                                        En, board, NC, Lsel, Pa, nullptr);
    // depth 0..2: C = conv(P, w_not2); fused L/sigmoid/P_next
    gemm_k<3><<<gBig, blk, 0, stream>>>(Pa, Mn2, 1024, nullptr, nullptr, 1024,
                                        En, board, NC, Lsel, Pb, nullptr);
    gemm_k<3><<<gBig, blk, 0, stream>>>(Pb, Mn2, 1024, nullptr, nullptr, 1024,
                                        En, board, NC, Lsel, Pa, nullptr);
    gemm_k<3><<<gBig, blk, 0, stream>>>(Pa, Mn2, 1024, nullptr, nullptr, 1024,
                                        En, board, NC, Lsel, Pb, nullptr);
    f16* feat = Xz; // Xz dead after En-GEMM
    // depth 3: writes feat = sigmoid only
    gemm_k<4><<<gBig, blk, 0, stream>>>(Pb, Mn2, 1024, nullptr, nullptr, 1024,
                                        En, board, nullptr, Lsel, nullptr, feat);
    // MLP layer 1 (padded to N=128) with fused leaky relu
    gemm_k<5><<<gMlp, blk, 0, stream>>>(feat, W1b, 1024, X1, nullptr, 128,
                                        nullptr, nullptr, nullptr, nullptr, nullptr, nullptr);
    mlp23<<<64, blk, 0, stream>>>(X1, W2, W3, out);
}

// Round 2
// 432.077 us; speedup vs baseline: 1.1703x; 1.1703x over previous
//
#include <hip/hip_runtime.h>
#include <cstdint>
#include <cstddef>

// ---------------------------------------------------------------------------
// NN_each_LN_exp: all 33x33 SAME convs on 32x32 maps are dense 1024x1024
// linear operators -> f16 MFMA GEMMs with fused epilogues.
// Row layout r = n*4 + k so the MFMA acc quad holds all 4 colors of one
// (n,o) cell -> sigmoid/mask fusion is lane-local.
// R2: A-operand synthesized at staging time (board one-hot / NC*s), XCD
// swizzle, s (8MB) instead of Pout (32MB), En in f16.
// ---------------------------------------------------------------------------

typedef _Float16 f16;
typedef __attribute__((ext_vector_type(8))) _Float16 f16x8;
typedef __attribute__((ext_vector_type(4))) float f32x4;

#define NB   4096          // batch
#define PIX  1024          // 32*32
#define MR   (NB * 4)      // color-expanded rows

__device__ __forceinline__ void gld_lds16(const void* g, void* l) {
    // async global->LDS, 16B/lane; LDS dst is wave-uniform base + lane*16
    __builtin_amdgcn_global_load_lds(
        (const __attribute__((address_space(1))) void*)g,
        (__attribute__((address_space(3))) void*)l, 16, 0, 0);
}

// Build the 4 conv matrices (1024x1024 f16): M[o][in] = w[a-i+16][b-j+16]
__global__ void build_mats(const float* __restrict__ we, const float* __restrict__ wn,
                           const float* __restrict__ wn2, const float* __restrict__ wem,
                           f16* __restrict__ Me, f16* __restrict__ Mn,
                           f16* __restrict__ Mn2, f16* __restrict__ Mem) {
    int idx = blockIdx.x * 256 + threadIdx.x;      // over 1024*1024
    int o = idx >> 10, in = idx & 1023;
    int i = o >> 5, j = o & 31, a = in >> 5, b = in & 31;
    int u = a - i + 16, v = b - j + 16;
    bool ok = (u >= 0) && (u < 33) && (v >= 0) && (v < 33);
    int w = u * 33 + v;
    float ve = 0.f, vn = 0.f, vn2 = 0.f, vem = 0.f;
    if (ok) { ve = we[w]; vn = wn[w]; vn2 = wn2[w]; vem = wem[w]; }
    Me[idx]  = (f16)ve;
    Mn[idx]  = (f16)vn;
    Mn2[idx] = (f16)vn2;
    Mem[idx] = (f16)vem;
}

// W1 (100,1024) fp32 -> padded (128,1024) f16
__global__ void build_w1(const float* __restrict__ W1, f16* __restrict__ W1b) {
    int idx = blockIdx.x * 256 + threadIdx.x;      // over 128*1024
    int j = idx >> 10, i = idx & 1023;
    W1b[idx] = (f16)(j < 100 ? W1[j * 1024 + i] : 0.f);
}

// dots (34,32,4096) int32, (v,h,b) -> board[n*1024+p] bytes, LDS transpose
__global__ void build_board(const int* __restrict__ dots, unsigned char* __restrict__ board) {
    __shared__ unsigned char tile[64][68];
    int t = threadIdx.x;
    int bp = blockIdx.x & 15, bn = blockIdx.x >> 4;   // grid 16*64 = 1024
    int p0 = bp * 64, n0 = bn * 64;
    int ln = t & 63, lp = t >> 6;                     // lp 0..3
#pragma unroll
    for (int j = 0; j < 16; j++) {
        int p = lp * 16 + j;
        tile[p][ln] = (unsigned char)dots[(size_t)(p0 + p) * 4096 + n0 + ln];
    }
    __syncthreads();
#pragma unroll
    for (int j = 0; j < 16; j++) {
        int n = lp * 16 + j;
        board[(size_t)(n0 + n) * 1024 + p0 + ln] = tile[ln][n];
    }
}

// ---------------------------------------------------------------------------
// GEMM: C(M x N) = A(M x K) * Mt(N x K)^T, f16 in, fp32 acc.
// BM=BN=128, BK=64, 256 thr = 4 waves (2x2 of 64x64), 16x16x32 MFMA.
// XOR-swizzled LDS chunks. 1D grid, XCD-banded decode (ypx = y-tiles/XCD).
// ASRC: 0 direct f16 (async gld_lds)  1 NC*s  2 each(board)  3 notm(board)
//       4 empty(board)
// MODE: 0 f16-out  2 stage1-fused  3 depth-fused  4 depth-final(feat)
//       5 f32-out+leakyrelu
// ---------------------------------------------------------------------------
template <int MODE, int ASRC>
__global__ void __launch_bounds__(256, 2) gemm_k(
    const f16* __restrict__ X, const f16* __restrict__ Mt, int K, int ypx,
    const f16* __restrict__ NCs, const f16* __restrict__ Sin,
    const unsigned char* __restrict__ board, const f16* __restrict__ En,
    float* __restrict__ Lsel, f16* __restrict__ outB, int ldo,
    float* __restrict__ outF) {
    __shared__ __attribute__((aligned(16))) char smem[32768];
    char* smA = smem;
    char* smB = smem + 16384;
    const int tid = threadIdx.x;
    const int wv = tid >> 6, ln = tid & 63;
    const int wm = wv >> 1, wn_ = wv & 1;
    const int lr = ln & 15, lq = ln >> 4;

    // XCD-banded swizzle: blocks i%8 -> XCD i%8 (round-robin); give each XCD
    // a contiguous band of row-tiles so its A working set fits the 4MB L2.
    int bi = blockIdx.x, bx, by;
    if (ypx > 0) {
        int xcd = bi & 7, slot = bi >> 3;
        bx = slot & 7;
        by = xcd * ypx + (slot >> 3);
    } else {
        bx = 0; by = bi;
    }
    const int rtile = by * 128, otile = bx * 128;

    const f32x4 fz = {0.f, 0.f, 0.f, 0.f};
    f32x4 acc[4][4];
#pragma unroll
    for (int i = 0; i < 4; i++)
#pragma unroll
        for (int j = 0; j < 4; j++) acc[i][j] = fz;

    for (int kb = 0; kb < K; kb += 64) {
#pragma unroll
        for (int t = 0; t < 4; t++) {
            int c = (wv * 4 + t) * 64 + ln;        // chunk id 0..1023
            int row = c >> 3;
            int gcol = (c & 7) ^ (row & 7);        // XOR-swizzled k-chunk
            int gr = rtile + row;
            int gk = kb + gcol * 8;
            if (ASRC == 0) {
                gld_lds16(X + (size_t)gr * K + gk, smA + (wv * 4 + t) * 1024);
            } else if (ASRC == 1) {                // A = NC * s
                f16x8 nc = *(const f16x8*)(NCs + (size_t)gr * PIX + gk);
                f16x8 sv = *(const f16x8*)(Sin + (size_t)(gr >> 2) * PIX + gk);
                *(f16x8*)(smA + c * 16) = nc * sv;
            } else {                               // one-hot from board
                int n = (ASRC == 4) ? gr : (gr >> 2);
                uint64_t bb = *(const uint64_t*)(board + (size_t)n * PIX + gk);
                int k1 = (gr & 3) + 1;
                f16x8 v;
#pragma unroll
                for (int j = 0; j < 8; j++) {
                    int bj = (int)((bb >> (8 * j)) & 0xff);
                    bool on = (ASRC == 2) ? (bj == k1)
                            : (ASRC == 3) ? (bj != 0 && bj != k1)
                                          : (bj == 0);
                    v[j] = on ? (f16)1.f : (f16)0.f;
                }
                *(f16x8*)(smA + c * 16) = v;
            }
            // B always async direct
            gld_lds16(Mt + (size_t)(otile + row) * K + gk, smB + (wv * 4 + t) * 1024);
        }
        __syncthreads();
#pragma unroll
        for (int kk = 0; kk < 2; kk++) {
            f16x8 af[4], bfr[4];
#pragma unroll
            for (int i = 0; i < 4; i++) {
                int rrow = wm * 64 + i * 16 + lr;
                int phys = (kk * 4 + lq) ^ (rrow & 7);
                af[i] = *(const f16x8*)(smA + rrow * 128 + phys * 16);
            }
#pragma unroll
            for (int j = 0; j < 4; j++) {
                int brow = wn_ * 64 + j * 16 + lr;
                int phys = (kk * 4 + lq) ^ (brow & 7);
                bfr[j] = *(const f16x8*)(smB + brow * 128 + phys * 16);
            }
#pragma unroll
            for (int i = 0; i < 4; i++)
#pragma unroll
                for (int j = 0; j < 4; j++)
                    acc[i][j] = __builtin_amdgcn_mfma_f32_16x16x32_f16(
                        af[i], bfr[j], acc[i][j], 0, 0, 0);
        }
        __syncthreads();
    }

    // epilogue: lane (i,j) holds C[rbase+v][o], v=0..3; rbase = n*4 in fused modes
#pragma unroll
    for (int i = 0; i < 4; i++) {
        int rbase = rtile + wm * 64 + i * 16 + lq * 4;
#pragma unroll
        for (int j = 0; j < 4; j++) {
            int o = otile + wn_ * 64 + j * 16 + lr;
            f32x4 a = acc[i][j];
            if (MODE == 0) {
#pragma unroll
                for (int v = 0; v < 4; v++)
                    outB[(size_t)(rbase + v) * ldo + o] = (f16)a[v];
            } else if (MODE == 5) {
#pragma unroll
                for (int v = 0; v < 4; v++) {
                    float x = a[v];
                    outF[(size_t)(rbase + v) * ldo + o] = x > 0.f ? x : 0.2f * x;
                }
            } else {  // 2, 3, 4: board-fused; exactly one color live per cell
                int n = rbase >> 2;
                size_t no = (size_t)n * PIX + o;
                int c = board[no];
                float E = (float)En[no];
                float asel = (c == 1) ? a[0] : (c == 2) ? a[1] : (c == 3) ? a[2] : a[3];
                float Lnew;
                if (MODE == 2) {
                    float ncsel = (float)NCs[(size_t)(rbase + (c > 0 ? c - 1 : 0)) * PIX + o];
                    Lnew = (c > 0) ? (asel + E - ncsel) : 0.f;   // L0 = each*(A+E-NC)
                } else {
                    Lnew = (c > 0) ? (Lsel[no] + E + asel) : 0.f; // L = each*(L+E+C)
                }
                float s = 1.f / (1.f + expf(-Lnew));              // empty -> 0.5
                if (MODE != 4) Lsel[no] = Lnew;
                outB[no] = (f16)s;                                 // s (or feat)
            }
        }
    }
}

// MLP layers 2+3: x2 = leaky(x1 @ W2^T); out = x2 @ W3^T. 64 batches/block.
__global__ void __launch_bounds__(256) mlp23(const float* __restrict__ X1,
                                             const float* __restrict__ W2,
                                             const float* __restrict__ W3,
                                             float* __restrict__ out) {
    __shared__ float sW2[10000];
    __shared__ float sW3[100];
    __shared__ float red[256];
    int t = threadIdx.x;
    for (int idx = t; idx < 10000; idx += 256) sW2[idx] = W2[idx];
    if (t < 100) sW3[t] = W3[t];
    __syncthreads();
    int nb = t >> 2, q = t & 3;
    int n = blockIdx.x * 64 + nb;
    const float* x1 = X1 + (size_t)n * 128;
    float xr[100];
#pragma unroll
    for (int i = 0; i < 100; i++) xr[i] = x1[i];
    float partial = 0.f;
    for (int jj = 0; jj < 25; jj++) {
        int j = q + jj * 4;
        const float* w2r = sW2 + j * 100;
        float acc2 = 0.f;
#pragma unroll
        for (int i = 0; i < 100; i++) acc2 += w2r[i] * xr[i];
        partial += sW3[j] * (acc2 > 0.f ? acc2 : 0.2f * acc2);
    }
    red[t] = partial;
    __syncthreads();
    if (q == 0) out[n] = red[t] + red[t + 1] + red[t + 2] + red[t + 3];
}

extern "C" void kernel_launch(void* const* d_in, const int* in_sizes, int n_in,
                              void* d_out, int out_size, void* d_ws, size_t ws_size,
                              hipStream_t stream) {
    (void)in_sizes; (void)n_in; (void)out_size; (void)ws_size;
    const int*   dots   = (const int*)d_in[0];
    const float* w_each = (const float*)d_in[1];
    const float* w_not  = (const float*)d_in[2];
    const float* w_not2 = (const float*)d_in[3];
    const float* w_emp  = (const float*)d_in[4];
    const float* W1 = (const float*)d_in[5];
    const float* W2 = (const float*)d_in[6];
    const float* W3 = (const float*)d_in[7];
    float* out = (float*)d_out;

    char* ws = (char*)d_ws;
    size_t off = 0;
    auto alloc = [&](size_t bytes) -> char* {
        char* p = ws + off;
        off += (bytes + 255) & ~(size_t)255;
        return p;
    };
    f16* Me   = (f16*)alloc((size_t)PIX * PIX * 2);
    f16* Mn   = (f16*)alloc((size_t)PIX * PIX * 2);
    f16* Mn2  = (f16*)alloc((size_t)PIX * PIX * 2);
    f16* Mem  = (f16*)alloc((size_t)PIX * PIX * 2);
    f16* W1b  = (f16*)alloc((size_t)128 * PIX * 2);
    unsigned char* board = (unsigned char*)alloc((size_t)NB * PIX);
    f16*   NC   = (f16*)alloc((size_t)MR * PIX * 2);
    f16*   En   = (f16*)alloc((size_t)NB * PIX * 2);
    f16*   Sa   = (f16*)alloc((size_t)NB * PIX * 2);
    f16*   Sb   = (f16*)alloc((size_t)NB * PIX * 2);
    f16*   feat = (f16*)alloc((size_t)NB * PIX * 2);
    float* Lsel = (float*)alloc((size_t)NB * PIX * 4);
    float* X1   = (float*)alloc((size_t)NB * 128 * 4);

    build_mats<<<4096, 256, 0, stream>>>(w_each, w_not, w_not2, w_emp, Me, Mn, Mn2, Mem);
    build_w1<<<512, 256, 0, stream>>>(W1, W1b);
    build_board<<<1024, 256, 0, stream>>>(dots, board);

    dim3 blk(256);
    // NC[r] = conv(notm[k], w_not): A from board, out f16
    gemm_k<0, 3><<<1024, blk, 0, stream>>>(nullptr, Mn, 1024, 16, nullptr, nullptr,
                                           board, nullptr, nullptr, NC, PIX, nullptr);
    // En[n] = conv(empty, w_empty): out f16
    gemm_k<0, 4><<<256, blk, 0, stream>>>(nullptr, Mem, 1024, 4, nullptr, nullptr,
                                          board, nullptr, nullptr, En, PIX, nullptr);
    // stage1: A = conv(each, w_each); fused L0/sigmoid -> s
    gemm_k<2, 2><<<1024, blk, 0, stream>>>(nullptr, Me, 1024, 16, NC, nullptr,
                                           board, En, Lsel, Sa, 0, nullptr);
    // depth 1..3: C = conv(NC*s, w_not2); fused L/sigmoid -> s'
    gemm_k<3, 1><<<1024, blk, 0, stream>>>(nullptr, Mn2, 1024, 16, NC, Sa,
                                           board, En, Lsel, Sb, 0, nullptr);
    gemm_k<3, 1><<<1024, blk, 0, stream>>>(nullptr, Mn2, 1024, 16, NC, Sb,
                                           board, En, Lsel, Sa, 0, nullptr);
    gemm_k<3, 1><<<1024, blk, 0, stream>>>(nullptr, Mn2, 1024, 16, NC, Sa,
                                           board, En, Lsel, Sb, 0, nullptr);
    // depth 4: writes feat = sigmoid only
    gemm_k<4, 1><<<1024, blk, 0, stream>>>(nullptr, Mn2, 1024, 16, NC, Sb,
                                           board, En, Lsel, feat, 0, nullptr);
    // MLP layer 1 (N padded to 128) with fused leaky relu
    gemm_k<5, 0><<<32, blk, 0, stream>>>(feat, W1b, 1024, 0, nullptr, nullptr,
                                         nullptr, nullptr, nullptr, nullptr, 128, X1);
    mlp23<<<64, blk, 0, stream>>>(X1, W2, W3, out);
}